// Round 11
// baseline (11899.226 us; speedup 1.0000x reference)
//
#include <hip/hip_runtime.h>

#define T_TOTAL 2048

typedef short bf16x8 __attribute__((ext_vector_type(8)));
typedef float f32x4 __attribute__((ext_vector_type(4)));
typedef unsigned long long ull;

// workspace layout (bytes)
#define OFF_WT  0ull                       // W slots bf16 [2][512 slot][64][16B] (1 MiB)
#define OFF_UT  (1ull<<20)                 // U slots bf16 [2][512 slot][64][16B] (1 MiB)
#define OFF_HG  (2ull<<20)                 // h exchange [(dir*4+bq)][par][8KB] (128 KiB)
#define OFF_HFR (OFF_HG + (128ull<<10))    // h frag at segment bound [(dir*4+bq)][8KB] (64 KiB)
#define OFF_CST (OFF_HG + (192ull<<10))    // c state f32 [2][64][256] (64 KiB)
#define OFF_CTR (OFF_HG + (256ull<<10))    // flags: 16 x 128 B
#define OFF_XW  (3ull<<20)                 // xw ring bf16 [Tseg][2][4][1024][16]
#define STEP_BYTES 262144ull               // one step of xw (bf16)

__device__ __forceinline__ unsigned short f2bf(float f){
  unsigned int u = __builtin_bit_cast(unsigned int, f);
  u += 0x7fffu + ((u>>16)&1u);
  return (unsigned short)(u>>16);
}
__device__ __forceinline__ float bfhi2f(unsigned int u){
  unsigned int v = u & 0xffff0000u; return __builtin_bit_cast(float, v);
}
__device__ __forceinline__ float bflo2f(unsigned int u){
  unsigned int v = u << 16; return __builtin_bit_cast(float, v);
}
__device__ __forceinline__ float sigf(float z){ return 1.0f/(1.0f + __expf(-z)); }
__device__ __forceinline__ float tanhf_(float z){ return 2.0f/(1.0f + __expf(-2.0f*z)) - 1.0f; }

// ---------------- prep: all 4 matrices -> fragment-slot layout -------------
__global__ __launch_bounds__(256) void kprep(const float* __restrict__ Wf, const float* __restrict__ Uf,
                                             const float* __restrict__ Wb, const float* __restrict__ Ub,
                                             unsigned short* __restrict__ ws){
  __shared__ float tile[64][65];
  int mat = blockIdx.z; // 0 Wf, 1 Wb, 2 Uf, 3 Ub
  const float* src = (mat==0)?Wf:(mat==1)?Wb:(mat==2)?Uf:Ub;
  unsigned short* dst = ws + ((mat<2)?0u:524288u) + (unsigned)(mat&1)*262144u;
  int c0 = blockIdx.x*64, k0 = blockIdx.y*64;
  int tx = threadIdx.x & 63, ty = threadIdx.x >> 6;
  #pragma unroll
  for (int j=0;j<16;j++){
    int r = j*4+ty;
    tile[r][tx] = src[(size_t)(k0+r)*1024 + (c0+tx)];
  }
  __syncthreads();
  #pragma unroll
  for (int j=0;j<16;j++){
    int r = j*4+ty;
    int col = c0+r, k = k0+tx;
    int cg = col>>4, ks = k>>5, kq = (k>>3)&3, e = k&7;
    dst[(size_t)(cg*8+ks)*512 + ((col&15)+16*kq)*8 + e] = f2bf(tile[tx][r]);
  }
}

// ---------------- xw GEMM: t-chunked, W resident, de-phi'd -----------------
__global__ __launch_bounds__(512) void kgemm(const float* __restrict__ x,
        const float* __restrict__ biasF, const float* __restrict__ biasB,
        const unsigned short* __restrict__ wsu, char* __restrict__ xw,
        int s0, int Tthis){
  __shared__ __align__(16) char smem[147456];
  char* abuf = smem + 131072;
  int chunk = blockIdx.x, dir = blockIdx.y, q = blockIdx.z;
  int tid = threadIdx.x, w = tid>>6, l = tid&63;
  int l15 = l&15;
  const char* WT = (const char*)(wsu + (size_t)dir*262144u);
  const float* bias = dir ? biasB : biasF;

  bf16x8 wfrA[8][4];
  bf16x8 wfrV[8][2];
  #pragma unroll
  for (int ct=0;ct<8;ct++){
    int cg = 8*w + ct;
    const char* base = WT + (size_t)cg*8192 + (size_t)l*16;
    #pragma unroll
    for (int ks=0;ks<4;ks++) wfrA[ct][ks] = *(const bf16x8*)(base + ks*1024);
    wfrV[ct][0] = *(const bf16x8*)(base + 4*1024);
    wfrV[ct][1] = *(const bf16x8*)(base + 5*1024);
    #pragma unroll
    for (int k2=0;k2<2;k2++){
      bf16x8 t = *(const bf16x8*)(base + (6+k2)*1024);
      *(bf16x8*)(smem + ((cg*2+k2)*1024 + l*16)) = t;
    }
  }
  float bv[8];
  #pragma unroll
  for (int ct=0;ct<8;ct++) bv[ct] = bias[128*w + ct*16 + l15];

  int b_loc = tid>>5, kk = (tid&31)*8;
  int b = q*16 + b_loc;
  int aslot = (kk>>5)*1024 + (b_loc + 16*((kk>>3)&3))*16;

  int nt = Tthis - chunk*64; if (nt > 64) nt = 64; if (nt < 0) nt = 0;
  if (nt > 0){
    int sg = s0 + chunk*64;
    int t_src = dir ? (T_TOTAL-1-sg) : sg;
    const float* px = x + ((size_t)b*T_TOTAL + t_src)*256 + kk;
    float4 v0 = *(const float4*)px;
    float4 v1 = *(const float4*)(px+4);
    uint4 pk;
    pk.x = (unsigned)f2bf(v0.x) | ((unsigned)f2bf(v0.y)<<16);
    pk.y = (unsigned)f2bf(v0.z) | ((unsigned)f2bf(v0.w)<<16);
    pk.z = (unsigned)f2bf(v1.x) | ((unsigned)f2bf(v1.y)<<16);
    pk.w = (unsigned)f2bf(v1.z) | ((unsigned)f2bf(v1.w)<<16);
    *(uint4*)(abuf + aslot) = pk;
  }
  __syncthreads();

  int p = 0;
  for (int tl=0; tl<nt; ++tl){
    float4 v0, v1;
    int have_next = (tl+1 < nt);
    if (have_next){
      int sg = s0 + chunk*64 + tl + 1;
      int t_src = dir ? (T_TOTAL-1-sg) : sg;
      const float* px = x + ((size_t)b*T_TOTAL + t_src)*256 + kk;
      v0 = *(const float4*)px;
      v1 = *(const float4*)(px+4);
    }
    char* outp = xw + (size_t)(chunk*64+tl)*STEP_BYTES + (size_t)dir*131072u + (size_t)q*32768u;
    #pragma unroll
    for (int half=0; half<2; ++half){
      f32x4 acc[4];
      #pragma unroll
      for (int ci=0;ci<4;ci++){
        float b0 = bv[half*4+ci];
        acc[ci][0]=b0; acc[ci][1]=b0; acc[ci][2]=b0; acc[ci][3]=b0;
      }
      #pragma unroll
      for (int ks=0;ks<4;ks++){
        bf16x8 a = *(const bf16x8*)(abuf + p*8192 + ks*1024 + l*16);
        #pragma unroll
        for (int ci=0;ci<4;ci++)
          acc[ci] = __builtin_amdgcn_mfma_f32_16x16x32_bf16(a, wfrA[half*4+ci][ks], acc[ci], 0, 0, 0);
      }
      #pragma unroll
      for (int k2=0;k2<2;k2++){
        bf16x8 a = *(const bf16x8*)(abuf + p*8192 + (4+k2)*1024 + l*16);
        #pragma unroll
        for (int ci=0;ci<4;ci++)
          acc[ci] = __builtin_amdgcn_mfma_f32_16x16x32_bf16(a, wfrV[half*4+ci][k2], acc[ci], 0, 0, 0);
      }
      #pragma unroll
      for (int k2=0;k2<2;k2++){
        bf16x8 a = *(const bf16x8*)(abuf + p*8192 + (6+k2)*1024 + l*16);
        #pragma unroll
        for (int ci=0;ci<4;ci++){
          bf16x8 bb = *(const bf16x8*)(smem + (((8*w+half*4+ci)*2+k2)*1024 + l*16));
          acc[ci] = __builtin_amdgcn_mfma_f32_16x16x32_bf16(a, bb, acc[ci], 0, 0, 0);
        }
      }
      #pragma unroll
      for (int ci=0;ci<4;ci++){
        int col = 128*w + (half*4+ci)*16 + l15;
        uint2 pk;
        pk.x = (unsigned)f2bf(acc[ci][0]) | ((unsigned)f2bf(acc[ci][1])<<16);
        pk.y = (unsigned)f2bf(acc[ci][2]) | ((unsigned)f2bf(acc[ci][3])<<16);
        *(uint2*)(outp + (size_t)col*32 + (l>>4)*8) = pk;
      }
    }
    if (have_next){
      uint4 pk;
      pk.x = (unsigned)f2bf(v0.x) | ((unsigned)f2bf(v0.y)<<16);
      pk.y = (unsigned)f2bf(v0.z) | ((unsigned)f2bf(v0.w)<<16);
      pk.z = (unsigned)f2bf(v1.x) | ((unsigned)f2bf(v1.y)<<16);
      pk.w = (unsigned)f2bf(v1.z) | ((unsigned)f2bf(v1.w)<<16);
      *(uint4*)(abuf + (p^1)*8192 + aslot) = pk;
    }
    __syncthreads();
    p ^= 1;
  }
}

// ---------------- recurrent scan: 16 blocks = hs(2) x dir(2) x bq(4) -------
// Pair (bid, bid^8) exchanges h halves each step via ONE 8-byte IC atomic
// per thread each way. MFMA split: own-half ks before the wait, partner
// half after -> partner store->flag->load RTT overlaps own MFMA + prefetch.
__global__ __launch_bounds__(512) void krec(const unsigned short* __restrict__ wsu,
        const char* __restrict__ xw, char* __restrict__ hg, char* __restrict__ hfr,
        float* __restrict__ cst, unsigned int* __restrict__ flags,
        float* __restrict__ out, int nsteps, int s0, int last){
  __shared__ __align__(16) char Bl[131072]; // [(w*2+gh)*8+ks][l*16]
  __shared__ __align__(16) char Ab[16384];  // A dbuf [par][half hs][4KB]
  int bid = blockIdx.x;
  int hs = bid>>3, dir = (bid>>2)&1, bq = bid&3;
  int tid = threadIdx.x, w = tid>>6, l = tid&63;
  int l15 = l&15;
  const char* UT = (const char*)(wsu + 524288u + (size_t)dir*262144u);

  // one-time B load: gate g col-group cg = g*16 + hs*8 + w
  bf16x8 Bf[2][8];
  #pragma unroll
  for (int g=0; g<2; g++){
    int cg = g*16 + hs*8 + w;
    #pragma unroll
    for (int ks=0;ks<8;ks++)
      Bf[g][ks] = *(const bf16x8*)(UT + (size_t)(cg*8+ks)*1024 + (size_t)l*16);
  }
  #pragma unroll
  for (int g=2; g<4; g++){
    int cg = g*16 + hs*8 + w;
    #pragma unroll
    for (int ks=0;ks<8;ks++){
      bf16x8 t = *(const bf16x8*)(UT + (size_t)(cg*8+ks)*1024 + (size_t)l*16);
      *(bf16x8*)(Bl + ((w*2+(g-2))*8+ks)*1024 + l*16) = t;
    }
  }

  unsigned int* myflag = flags + bid*32;
  unsigned int* pflag  = flags + (bid^8)*32;
  char* hgreg = hg + (size_t)(dir*4+bq)*16384u;   // [par][8KB]

  int jh = w*16 + l15;               // j within half [0,128)
  int ksl = jh>>5, kqh = (jh>>3)&3, eh = jh&7;
  int jfull = hs*128 + jh;
  int bg = l>>4;                     // batch quad 0..3 (rows 4bg..4bg+3)

  float c_[4];
  if (s0 == 0){
    #pragma unroll
    for (int r=0;r<4;r++) c_[r] = 0.0f;
    *(uint4*)(Ab + tid*16) = make_uint4(0u,0u,0u,0u);
  } else {
    *(uint4*)(Ab + tid*16) = *(const uint4*)(hfr + (size_t)(dir*4+bq)*8192u + tid*16);
    #pragma unroll
    for (int r=0;r<4;r++)
      c_[r] = cst[((size_t)dir*64 + bq*16 + bg*4 + r)*256 + jfull];
  }
  __syncthreads();

  const char* XW = xw + (size_t)dir*131072u + (size_t)bq*32768u;
  uint2 xv[4];
  #pragma unroll
  for (int g=0;g<4;g++){
    int col = g*256 + hs*128 + w*16 + l15;
    xv[g] = *(const uint2*)(XW + (size_t)col*32 + bg*8);
  }

  for (int lt=0; lt<nsteps; ++lt){
    int par = lt&1, parn = par^1;
    f32x4 acc[4];
    #pragma unroll
    for (int g=0;g<4;g++){
      uint2 v = xv[g];
      acc[g][0]=bflo2f(v.x); acc[g][1]=bfhi2f(v.x);
      acc[g][2]=bflo2f(v.y); acc[g][3]=bfhi2f(v.y);
    }
    // own-half MFMA: ks in [4hs, 4hs+4) -- A slots written locally last step
    #pragma unroll
    for (int k2=0;k2<4;k2++){
      int ks = 4*hs + k2;
      bf16x8 a = *(const bf16x8*)(Ab + par*8192 + ks*1024 + l*16);
      acc[0] = __builtin_amdgcn_mfma_f32_16x16x32_bf16(a, Bf[0][ks], acc[0], 0, 0, 0);
      acc[1] = __builtin_amdgcn_mfma_f32_16x16x32_bf16(a, Bf[1][ks], acc[1], 0, 0, 0);
      bf16x8 b2 = *(const bf16x8*)(Bl + ((w*2+0)*8+ks)*1024 + l*16);
      acc[2] = __builtin_amdgcn_mfma_f32_16x16x32_bf16(a, b2, acc[2], 0, 0, 0);
      bf16x8 b3 = *(const bf16x8*)(Bl + ((w*2+1)*8+ks)*1024 + l*16);
      acc[3] = __builtin_amdgcn_mfma_f32_16x16x32_bf16(a, b3, acc[3], 0, 0, 0);
    }
    { // xw prefetch for next step (in flight during partner wait)
      int ltn = (lt+1 < nsteps) ? (lt+1) : lt;
      #pragma unroll
      for (int g=0;g<4;g++){
        int col = g*256 + hs*128 + w*16 + l15;
        xv[g] = *(const uint2*)(XW + (size_t)ltn*STEP_BYTES + (size_t)col*32 + bg*8);
      }
    }
    // partner wait + 8B/thread load (lt==0: A full from init, no wait)
    if (lt > 0){
      if (tid == 0){
        unsigned want = (unsigned)lt;
        while (__hip_atomic_load(pflag, __ATOMIC_RELAXED, __HIP_MEMORY_SCOPE_AGENT) < want)
          ;
      }
      __syncthreads();
      ull v = __hip_atomic_load((const ull*)(hgreg + (size_t)par*8192u + (1-hs)*4096 + tid*8),
                                __ATOMIC_RELAXED, __HIP_MEMORY_SCOPE_AGENT);
      *(ull*)(Ab + par*8192 + (1-hs)*4096 + tid*8) = v;
      __syncthreads();
    }
    // partner-half MFMA: ks in [4(1-hs), 4(1-hs)+4)
    #pragma unroll
    for (int k2=0;k2<4;k2++){
      int ks = 4*(1-hs) + k2;
      bf16x8 a = *(const bf16x8*)(Ab + par*8192 + ks*1024 + l*16);
      acc[0] = __builtin_amdgcn_mfma_f32_16x16x32_bf16(a, Bf[0][ks], acc[0], 0, 0, 0);
      acc[1] = __builtin_amdgcn_mfma_f32_16x16x32_bf16(a, Bf[1][ks], acc[1], 0, 0, 0);
      bf16x8 b2 = *(const bf16x8*)(Bl + ((w*2+0)*8+ks)*1024 + l*16);
      acc[2] = __builtin_amdgcn_mfma_f32_16x16x32_bf16(a, b2, acc[2], 0, 0, 0);
      bf16x8 b3 = *(const bf16x8*)(Bl + ((w*2+1)*8+ks)*1024 + l*16);
      acc[3] = __builtin_amdgcn_mfma_f32_16x16x32_bf16(a, b3, acc[3], 0, 0, 0);
    }
    float hv[4];
    #pragma unroll
    for (int r=0;r<4;r++){
      float ig = sigf(acc[0][r]);
      float fg = sigf(acc[1][r]);
      float gg = tanhf_(acc[2][r]);
      float og = sigf(acc[3][r]);
      float cn = fg*c_[r] + ig*gg;
      c_[r] = cn;
      hv[r] = og*tanhf_(cn);
    }

    if (lt == nsteps-1){
      if (last){
        #pragma unroll
        for (int r=0;r<4;r++)
          out[(size_t)(bq*16 + bg*4 + r)*512 + dir*256 + jfull] = hv[r];
      } else {
        char* hw = hfr + (size_t)(dir*4+bq)*8192u + hs*4096;
        #pragma unroll
        for (int r=0;r<4;r++)
          *(unsigned short*)(hw + ksl*1024 + (bg*4+r + 16*kqh)*16 + eh*2) = f2bf(hv[r]);
        #pragma unroll
        for (int r=0;r<4;r++)
          cst[((size_t)dir*64 + bq*16 + bg*4 + r)*256 + jfull] = c_[r];
      }
      break;
    }

    // tail: own half h(t+1) -> LDS A[parn]; pack -> ONE 8B IC atomic/thread
    {
      char* al = Ab + parn*8192 + hs*4096;
      #pragma unroll
      for (int r=0;r<4;r++){
        unsigned short hb = f2bf(hv[r]);
        *(unsigned short*)(al + ksl*1024 + (bg*4+r + 16*kqh)*16 + eh*2) = hb;
      }
    }
    __syncthreads();
    {
      ull pv = *(const ull*)(Ab + parn*8192 + hs*4096 + tid*8);
      __hip_atomic_store((ull*)(hgreg + (size_t)parn*8192u + hs*4096 + tid*8), pv,
                         __ATOMIC_RELAXED, __HIP_MEMORY_SCOPE_AGENT);
    }
    asm volatile("s_waitcnt vmcnt(0)" ::: "memory");
    __syncthreads();
    if (tid == 0)
      __hip_atomic_store(myflag, (unsigned)(lt+1),
                         __ATOMIC_RELAXED, __HIP_MEMORY_SCOPE_AGENT);
  }
}

extern "C" void kernel_launch(void* const* d_in, const int* in_sizes, int n_in,
                              void* d_out, int out_size, void* d_ws, size_t ws_size,
                              hipStream_t stream){
  (void)in_sizes; (void)n_in; (void)out_size;
  const float* x   = (const float*)d_in[0];
  const float* Wf  = (const float*)d_in[1];
  const float* Uf  = (const float*)d_in[2];
  const float* bf_ = (const float*)d_in[3];
  const float* Wb  = (const float*)d_in[4];
  const float* Ub  = (const float*)d_in[5];
  const float* bb  = (const float*)d_in[6];
  float* out = (float*)d_out;
  char* ws = (char*)d_ws;
  unsigned short* wsu = (unsigned short*)ws;
  char* hg  = ws + OFF_HG;
  char* hfr = ws + OFF_HFR;
  float* cst = (float*)(ws + OFF_CST);
  unsigned int* flags = (unsigned int*)(ws + OFF_CTR);
  char* xwb = ws + OFF_XW;

  kprep<<<dim3(16,4,4), 256, 0, stream>>>(Wf, Uf, Wb, Ub, wsu);

  long long avail = (long long)ws_size - (long long)OFF_XW;
  int Tseg = (avail > 0) ? (int)(avail / (long long)STEP_BYTES) : 1;
  if (Tseg < 1) Tseg = 1;
  if (Tseg > T_TOTAL) Tseg = T_TOTAL;
  int nseg = (T_TOTAL + Tseg - 1)/Tseg;
  int s0 = 0;
  for (int seg=0; seg<nseg; ++seg){
    int Tthis = (T_TOTAL - s0 < Tseg) ? (T_TOTAL - s0) : Tseg;
    int nchunk = (Tthis + 63)/64;
    (void)hipMemsetAsync(flags, 0, 2048, stream);
    kgemm<<<dim3(nchunk,2,4), 512, 0, stream>>>(x, bf_, bb, wsu, xwb, s0, Tthis);
    krec<<<dim3(16), 512, 0, stream>>>(wsu, xwb, hg, hfr, cst, flags, out, Tthis, s0,
                                       (seg==nseg-1)?1:0);
    s0 += Tthis;
  }
}

// Round 13
// 6116.538 us; speedup vs baseline: 1.9454x; 1.9454x over previous
//
#include <hip/hip_runtime.h>

#define T_TOTAL 2048

typedef short bf16x8 __attribute__((ext_vector_type(8)));
typedef float f32x4 __attribute__((ext_vector_type(4)));
typedef unsigned long long ull;

// workspace layout (bytes)
#define OFF_WT  0ull                       // W slots bf16 [2][512 slot][64][16B] (1 MiB)
#define OFF_UT  (1ull<<20)                 // U slots bf16 [2][512 slot][64][16B] (1 MiB)
#define OFF_EX  (2ull<<20)                 // ex slots [grp8][par2][half2][8KB] (256 KiB)
#define OFF_HFR (OFF_EX + (256ull<<10))    // h frag at segment bound [grp8][8KB] (64 KiB)
#define OFF_CST (OFF_HFR + (64ull<<10))    // c state f32 [2][64][256] (64 KiB)
#define OFF_XW  (3ull<<20)                 // xw ring bf16 [Tseg][2][4][1024][16]
#define STEP_BYTES 262144ull               // one step of xw (bf16)

__device__ __forceinline__ unsigned short f2bf(float f){
  unsigned int u = __builtin_bit_cast(unsigned int, f);
  u += 0x7fffu + ((u>>16)&1u);
  return (unsigned short)(u>>16);
}
__device__ __forceinline__ float bfhi2f(unsigned int u){
  unsigned int v = u & 0xffff0000u; return __builtin_bit_cast(float, v);
}
__device__ __forceinline__ float bflo2f(unsigned int u){
  unsigned int v = u << 16; return __builtin_bit_cast(float, v);
}
__device__ __forceinline__ float sigf(float z){ return 1.0f/(1.0f + __expf(-z)); }
__device__ __forceinline__ float tanhf_(float z){ return 2.0f/(1.0f + __expf(-2.0f*z)) - 1.0f; }

// ---------------- prep: all 4 matrices -> fragment-slot layout -------------
__global__ __launch_bounds__(256) void kprep(const float* __restrict__ Wf, const float* __restrict__ Uf,
                                             const float* __restrict__ Wb, const float* __restrict__ Ub,
                                             unsigned short* __restrict__ ws){
  __shared__ float tile[64][65];
  int mat = blockIdx.z; // 0 Wf, 1 Wb, 2 Uf, 3 Ub
  const float* src = (mat==0)?Wf:(mat==1)?Wb:(mat==2)?Uf:Ub;
  unsigned short* dst = ws + ((mat<2)?0u:524288u) + (unsigned)(mat&1)*262144u;
  int c0 = blockIdx.x*64, k0 = blockIdx.y*64;
  int tx = threadIdx.x & 63, ty = threadIdx.x >> 6;
  #pragma unroll
  for (int j=0;j<16;j++){
    int r = j*4+ty;
    tile[r][tx] = src[(size_t)(k0+r)*1024 + (c0+tx)];
  }
  __syncthreads();
  #pragma unroll
  for (int j=0;j<16;j++){
    int r = j*4+ty;
    int col = c0+r, k = k0+tx;
    int cg = col>>4, ks = k>>5, kq = (k>>3)&3, e = k&7;
    dst[(size_t)(cg*8+ks)*512 + ((col&15)+16*kq)*8 + e] = f2bf(tile[tx][r]);
  }
}

// ---------------- xw GEMM: t-chunked, W resident, de-phi'd -----------------
__global__ __launch_bounds__(512) void kgemm(const float* __restrict__ x,
        const float* __restrict__ biasF, const float* __restrict__ biasB,
        const unsigned short* __restrict__ wsu, char* __restrict__ xw,
        int s0, int Tthis){
  __shared__ __align__(16) char smem[147456];
  char* abuf = smem + 131072;
  int chunk = blockIdx.x, dir = blockIdx.y, q = blockIdx.z;
  int tid = threadIdx.x, w = tid>>6, l = tid&63;
  int l15 = l&15;
  const char* WT = (const char*)(wsu + (size_t)dir*262144u);
  const float* bias = dir ? biasB : biasF;

  bf16x8 wfrA[8][4];
  bf16x8 wfrV[8][2];
  #pragma unroll
  for (int ct=0;ct<8;ct++){
    int cg = 8*w + ct;
    const char* base = WT + (size_t)cg*8192 + (size_t)l*16;
    #pragma unroll
    for (int ks=0;ks<4;ks++) wfrA[ct][ks] = *(const bf16x8*)(base + ks*1024);
    wfrV[ct][0] = *(const bf16x8*)(base + 4*1024);
    wfrV[ct][1] = *(const bf16x8*)(base + 5*1024);
    #pragma unroll
    for (int k2=0;k2<2;k2++){
      bf16x8 t = *(const bf16x8*)(base + (6+k2)*1024);
      *(bf16x8*)(smem + ((cg*2+k2)*1024 + l*16)) = t;
    }
  }
  float bv[8];
  #pragma unroll
  for (int ct=0;ct<8;ct++) bv[ct] = bias[128*w + ct*16 + l15];

  int b_loc = tid>>5, kk = (tid&31)*8;
  int b = q*16 + b_loc;
  int aslot = (kk>>5)*1024 + (b_loc + 16*((kk>>3)&3))*16;

  int nt = Tthis - chunk*64; if (nt > 64) nt = 64; if (nt < 0) nt = 0;
  if (nt > 0){
    int sg = s0 + chunk*64;
    int t_src = dir ? (T_TOTAL-1-sg) : sg;
    const float* px = x + ((size_t)b*T_TOTAL + t_src)*256 + kk;
    float4 v0 = *(const float4*)px;
    float4 v1 = *(const float4*)(px+4);
    uint4 pk;
    pk.x = (unsigned)f2bf(v0.x) | ((unsigned)f2bf(v0.y)<<16);
    pk.y = (unsigned)f2bf(v0.z) | ((unsigned)f2bf(v0.w)<<16);
    pk.z = (unsigned)f2bf(v1.x) | ((unsigned)f2bf(v1.y)<<16);
    pk.w = (unsigned)f2bf(v1.z) | ((unsigned)f2bf(v1.w)<<16);
    *(uint4*)(abuf + aslot) = pk;
  }
  __syncthreads();

  int p = 0;
  for (int tl=0; tl<nt; ++tl){
    float4 v0, v1;
    int have_next = (tl+1 < nt);
    if (have_next){
      int sg = s0 + chunk*64 + tl + 1;
      int t_src = dir ? (T_TOTAL-1-sg) : sg;
      const float* px = x + ((size_t)b*T_TOTAL + t_src)*256 + kk;
      v0 = *(const float4*)px;
      v1 = *(const float4*)(px+4);
    }
    char* outp = xw + (size_t)(chunk*64+tl)*STEP_BYTES + (size_t)dir*131072u + (size_t)q*32768u;
    #pragma unroll
    for (int half=0; half<2; ++half){
      f32x4 acc[4];
      #pragma unroll
      for (int ci=0;ci<4;ci++){
        float b0 = bv[half*4+ci];
        acc[ci][0]=b0; acc[ci][1]=b0; acc[ci][2]=b0; acc[ci][3]=b0;
      }
      #pragma unroll
      for (int ks=0;ks<4;ks++){
        bf16x8 a = *(const bf16x8*)(abuf + p*8192 + ks*1024 + l*16);
        #pragma unroll
        for (int ci=0;ci<4;ci++)
          acc[ci] = __builtin_amdgcn_mfma_f32_16x16x32_bf16(a, wfrA[half*4+ci][ks], acc[ci], 0, 0, 0);
      }
      #pragma unroll
      for (int k2=0;k2<2;k2++){
        bf16x8 a = *(const bf16x8*)(abuf + p*8192 + (4+k2)*1024 + l*16);
        #pragma unroll
        for (int ci=0;ci<4;ci++)
          acc[ci] = __builtin_amdgcn_mfma_f32_16x16x32_bf16(a, wfrV[half*4+ci][k2], acc[ci], 0, 0, 0);
      }
      #pragma unroll
      for (int k2=0;k2<2;k2++){
        bf16x8 a = *(const bf16x8*)(abuf + p*8192 + (6+k2)*1024 + l*16);
        #pragma unroll
        for (int ci=0;ci<4;ci++){
          bf16x8 bb = *(const bf16x8*)(smem + (((8*w+half*4+ci)*2+k2)*1024 + l*16));
          acc[ci] = __builtin_amdgcn_mfma_f32_16x16x32_bf16(a, bb, acc[ci], 0, 0, 0);
        }
      }
      #pragma unroll
      for (int ci=0;ci<4;ci++){
        int col = 128*w + (half*4+ci)*16 + l15;
        uint2 pk;
        pk.x = (unsigned)f2bf(acc[ci][0]) | ((unsigned)f2bf(acc[ci][1])<<16);
        pk.y = (unsigned)f2bf(acc[ci][2]) | ((unsigned)f2bf(acc[ci][3])<<16);
        *(uint2*)(outp + (size_t)col*32 + (l>>4)*8) = pk;
      }
    }
    if (have_next){
      uint4 pk;
      pk.x = (unsigned)f2bf(v0.x) | ((unsigned)f2bf(v0.y)<<16);
      pk.y = (unsigned)f2bf(v0.z) | ((unsigned)f2bf(v0.w)<<16);
      pk.z = (unsigned)f2bf(v1.x) | ((unsigned)f2bf(v1.y)<<16);
      pk.w = (unsigned)f2bf(v1.z) | ((unsigned)f2bf(v1.w)<<16);
      *(uint4*)(abuf + (p^1)*8192 + aslot) = pk;
    }
    __syncthreads();
    p ^= 1;
  }
}

// ---------------- recurrent scan: 16 blocks = hs(2) x dir(2) x bq(4) -------
// Pair (hs, 1-hs) of the same (dir,bq). Exchange via SEQ-TAGGED 8B IC slots:
// each slot = 2 bf16 h + 16-bit step tag; reader polls its own slots until
// tag matches -> no flags, no fences, no tid0 serialization. Parity dbuf.
__global__ __launch_bounds__(512) void krec(const unsigned short* __restrict__ wsu,
        const char* __restrict__ xw, char* __restrict__ ex, char* __restrict__ hfr,
        float* __restrict__ cst, float* __restrict__ out,
        int nsteps, int s0, int last){
  __shared__ __align__(16) char Bl[131072]; // [(w*2+gh)*8+ks_phys][l*16]
  __shared__ __align__(16) char Ab[16384];  // A dbuf [par][ks_phys 0..7][1KB]
  int bid = blockIdx.x;
  int hs = bid>>3, dir = (bid>>2)&1, bq = bid&3;
  int tid = threadIdx.x, w = tid>>6, l = tid&63;
  int l15 = l&15;
  const char* UT = (const char*)(wsu + 524288u + (size_t)dir*262144u);

  // B frags, gates 0,1: [k2 0..3]=own-k (ks 4hs+k2), [4+k2]=partner-k. All
  // MFMA indices compile-time (no runtime-indexed register arrays).
  bf16x8 Bf[2][8];
  #pragma unroll
  for (int g=0; g<2; g++){
    int cg = g*16 + hs*8 + w;
    const char* base = UT + (size_t)cg*8192 + (size_t)l*16;
    #pragma unroll
    for (int k2=0;k2<4;k2++){
      Bf[g][k2]   = *(const bf16x8*)(base + (size_t)(4*hs+k2)*1024);
      Bf[g][4+k2] = *(const bf16x8*)(base + (size_t)(4*(1-hs)+k2)*1024);
    }
  }
  // gates 2,3 -> LDS (physical ks layout)
  #pragma unroll
  for (int g=2; g<4; g++){
    int cg = g*16 + hs*8 + w;
    #pragma unroll
    for (int ks=0;ks<8;ks++){
      bf16x8 t = *(const bf16x8*)(UT + (size_t)(cg*8+ks)*1024 + (size_t)l*16);
      *(bf16x8*)(Bl + ((w*2+(g-2))*8+ks)*1024 + l*16) = t;
    }
  }

  int grp = dir*4 + bq;
  char* exbase = ex + (size_t)grp*32768u;   // [par][half][8KB]

  int jh = w*16 + l15;               // j within half [0,128)
  int ksl = jh>>5, kqh = (jh>>3)&3, eh = jh&7;
  int jfull = hs*128 + jh;
  int bg = l>>4;                     // batch quad 0..3 (rows 4bg..4bg+3)
  int offr0 = ksl*1024 + (bg*4 + 0 + 16*kqh)*16 + eh*2;
  int offr1 = ksl*1024 + (bg*4 + 1 + 16*kqh)*16 + eh*2;
  int offr2 = ksl*1024 + (bg*4 + 2 + 16*kqh)*16 + eh*2;
  int offr3 = ksl*1024 + (bg*4 + 3 + 16*kqh)*16 + eh*2;

  float c_[4];
  if (s0 == 0){
    #pragma unroll
    for (int r=0;r<4;r++) c_[r] = 0.0f;
    *(uint4*)(Ab + tid*16) = make_uint4(0u,0u,0u,0u);
  } else {
    *(uint4*)(Ab + tid*16) = *(const uint4*)(hfr + (size_t)grp*8192u + tid*16);
    #pragma unroll
    for (int r=0;r<4;r++)
      c_[r] = cst[((size_t)dir*64 + bq*16 + bg*4 + r)*256 + jfull];
  }
  __syncthreads();

  const char* XW = xw + (size_t)dir*131072u + (size_t)bq*32768u;
  uint2 xv[4];
  #pragma unroll
  for (int g=0;g<4;g++){
    int col = g*256 + hs*128 + w*16 + l15;
    xv[g] = *(const uint2*)(XW + (size_t)col*32 + bg*8);
  }

  // precomputed LDS bases
  const char* Bl0 = Bl + (w*2+0)*8192 + l*16;
  const char* Bl1 = Bl + (w*2+1)*8192 + l*16;
  int ownkoff = hs*4096, partkoff = (1-hs)*4096;

  for (int lt=0; lt<nsteps; ++lt){
    int par = lt&1, parn = par^1;
    unsigned short wantu = (unsigned short)(unsigned)(s0 + lt);
    f32x4 acc[4];
    #pragma unroll
    for (int g=0;g<4;g++){
      uint2 v = xv[g];
      acc[g][0]=bflo2f(v.x); acc[g][1]=bfhi2f(v.x);
      acc[g][2]=bflo2f(v.y); acc[g][3]=bfhi2f(v.y);
    }
    // own-half MFMA (A own half written locally at prev tail; init at lt=0)
    {
      const char* Aown = Ab + par*8192 + ownkoff + l*16;
      #pragma unroll
      for (int k2=0;k2<4;k2++){
        bf16x8 a = *(const bf16x8*)(Aown + k2*1024);
        acc[0] = __builtin_amdgcn_mfma_f32_16x16x32_bf16(a, Bf[0][k2], acc[0], 0, 0, 0);
        acc[1] = __builtin_amdgcn_mfma_f32_16x16x32_bf16(a, Bf[1][k2], acc[1], 0, 0, 0);
        bf16x8 b2 = *(const bf16x8*)(Bl0 + ownkoff + k2*1024);
        acc[2] = __builtin_amdgcn_mfma_f32_16x16x32_bf16(a, b2, acc[2], 0, 0, 0);
        bf16x8 b3 = *(const bf16x8*)(Bl1 + ownkoff + k2*1024);
        acc[3] = __builtin_amdgcn_mfma_f32_16x16x32_bf16(a, b3, acc[3], 0, 0, 0);
      }
    }
    // partner half: poll seq-tagged slots (lt==0: LDS already full from init)
    if (lt > 0){
      const ull* exr = (const ull*)(exbase + (size_t)par*16384u + (size_t)(1-hs)*8192u) + 2*tid;
      ull v0, v1;
      for(;;){
        v0 = __hip_atomic_load(exr, __ATOMIC_RELAXED, __HIP_MEMORY_SCOPE_AGENT);
        if ((unsigned short)(v0>>48) == wantu) break;
        __builtin_amdgcn_s_sleep(1);
      }
      for(;;){
        v1 = __hip_atomic_load(exr+1, __ATOMIC_RELAXED, __HIP_MEMORY_SCOPE_AGENT);
        if ((unsigned short)(v1>>48) == wantu) break;
        __builtin_amdgcn_s_sleep(1);
      }
      char* ap = Ab + par*8192 + partkoff;
      *(unsigned short*)(ap + offr0) = (unsigned short)v0;
      *(unsigned short*)(ap + offr1) = (unsigned short)(v0>>16);
      *(unsigned short*)(ap + offr2) = (unsigned short)v1;
      *(unsigned short*)(ap + offr3) = (unsigned short)(v1>>16);
    }
    __syncthreads();
    // partner-half MFMA
    {
      const char* Apart = Ab + par*8192 + partkoff + l*16;
      #pragma unroll
      for (int k2=0;k2<4;k2++){
        bf16x8 a = *(const bf16x8*)(Apart + k2*1024);
        acc[0] = __builtin_amdgcn_mfma_f32_16x16x32_bf16(a, Bf[0][4+k2], acc[0], 0, 0, 0);
        acc[1] = __builtin_amdgcn_mfma_f32_16x16x32_bf16(a, Bf[1][4+k2], acc[1], 0, 0, 0);
        bf16x8 b2 = *(const bf16x8*)(Bl0 + partkoff + k2*1024);
        acc[2] = __builtin_amdgcn_mfma_f32_16x16x32_bf16(a, b2, acc[2], 0, 0, 0);
        bf16x8 b3 = *(const bf16x8*)(Bl1 + partkoff + k2*1024);
        acc[3] = __builtin_amdgcn_mfma_f32_16x16x32_bf16(a, b3, acc[3], 0, 0, 0);
      }
    }
    float hv[4];
    #pragma unroll
    for (int r=0;r<4;r++){
      float ig = sigf(acc[0][r]);
      float fg = sigf(acc[1][r]);
      float gg = tanhf_(acc[2][r]);
      float og = sigf(acc[3][r]);
      float cn = fg*c_[r] + ig*gg;
      c_[r] = cn;
      hv[r] = og*tanhf_(cn);
    }

    if (lt == nsteps-1){
      if (last){
        #pragma unroll
        for (int r=0;r<4;r++)
          out[(size_t)(bq*16 + bg*4 + r)*512 + dir*256 + jfull] = hv[r];
      } else {
        char* hw = hfr + (size_t)grp*8192u + hs*4096;
        *(unsigned short*)(hw + offr0) = f2bf(hv[0]);
        *(unsigned short*)(hw + offr1) = f2bf(hv[1]);
        *(unsigned short*)(hw + offr2) = f2bf(hv[2]);
        *(unsigned short*)(hw + offr3) = f2bf(hv[3]);
        #pragma unroll
        for (int r=0;r<4;r++)
          cst[((size_t)dir*64 + bq*16 + bg*4 + r)*256 + jfull] = c_[r];
      }
      break;
    }

    // publish own half h(t+1): 2x 8B seq-tagged IC atomic stores, ASAP
    unsigned short hb0 = f2bf(hv[0]), hb1 = f2bf(hv[1]);
    unsigned short hb2 = f2bf(hv[2]), hb3 = f2bf(hv[3]);
    {
      ull tag = ((ull)(unsigned short)(unsigned)(s0+lt+1)) << 48;
      ull p0 = (ull)hb0 | ((ull)hb1<<16) | tag;
      ull p1 = (ull)hb2 | ((ull)hb3<<16) | tag;
      ull* exw = (ull*)(exbase + (size_t)parn*16384u + (size_t)hs*8192u) + 2*tid;
      __hip_atomic_store(exw,   p0, __ATOMIC_RELAXED, __HIP_MEMORY_SCOPE_AGENT);
      __hip_atomic_store(exw+1, p1, __ATOMIC_RELAXED, __HIP_MEMORY_SCOPE_AGENT);
    }
    // own half -> LDS A[parn]
    {
      char* al = Ab + parn*8192 + ownkoff;
      *(unsigned short*)(al + offr0) = hb0;
      *(unsigned short*)(al + offr1) = hb1;
      *(unsigned short*)(al + offr2) = hb2;
      *(unsigned short*)(al + offr3) = hb3;
    }
    // xw prefetch for next step
    #pragma unroll
    for (int g=0;g<4;g++){
      int col = g*256 + hs*128 + w*16 + l15;
      xv[g] = *(const uint2*)(XW + (size_t)(lt+1)*STEP_BYTES + (size_t)col*32 + bg*8);
    }
    __syncthreads();
  }
}

extern "C" void kernel_launch(void* const* d_in, const int* in_sizes, int n_in,
                              void* d_out, int out_size, void* d_ws, size_t ws_size,
                              hipStream_t stream){
  (void)in_sizes; (void)n_in; (void)out_size;
  const float* x   = (const float*)d_in[0];
  const float* Wf  = (const float*)d_in[1];
  const float* Uf  = (const float*)d_in[2];
  const float* bf_ = (const float*)d_in[3];
  const float* Wb  = (const float*)d_in[4];
  const float* Ub  = (const float*)d_in[5];
  const float* bb  = (const float*)d_in[6];
  float* out = (float*)d_out;
  char* ws = (char*)d_ws;
  unsigned short* wsu = (unsigned short*)ws;
  char* ex  = ws + OFF_EX;
  char* hfr = ws + OFF_HFR;
  float* cst = (float*)(ws + OFF_CST);
  char* xwb = ws + OFF_XW;

  (void)hipMemsetAsync(ex, 0, 262144, stream);   // seq tags: no stale matches
  kprep<<<dim3(16,4,4), 256, 0, stream>>>(Wf, Uf, Wb, Ub, wsu);

  long long avail = (long long)ws_size - (long long)OFF_XW;
  int Tseg = (avail > 0) ? (int)(avail / (long long)STEP_BYTES) : 1;
  if (Tseg < 1) Tseg = 1;
  if (Tseg > T_TOTAL) Tseg = T_TOTAL;
  int nseg = (T_TOTAL + Tseg - 1)/Tseg;
  int s0 = 0;
  for (int seg=0; seg<nseg; ++seg){
    int Tthis = (T_TOTAL - s0 < Tseg) ? (T_TOTAL - s0) : Tseg;
    int nchunk = (Tthis + 63)/64;
    kgemm<<<dim3(nchunk,2,4), 512, 0, stream>>>(x, bf_, bb, wsu, xwb, s0, Tthis);
    krec<<<dim3(16), 512, 0, stream>>>(wsu, xwb, ex, hfr, cst, out, Tthis, s0,
                                       (seg==nseg-1)?1:0);
    s0 += Tthis;
  }
}